// Round 8
// baseline (160.187 us; speedup 1.0000x reference)
//
#include <hip/hip_runtime.h>
#include <hip/hip_bf16.h>
#include <stdint.h>

#define B_DIM 8192
#define D_DIM 2048
#define U_DIM 2048
#define KWORDS 64            // bit path: 2048 bits = 64 u32 words

typedef int v4i  __attribute__((ext_vector_type(4)));
typedef int v16i __attribute__((ext_vector_type(16)));

// Async global->LDS DMA, 16B per lane. LDS dest is wave-uniform base + lane*16;
// global src may be per-lane arbitrary (we fold the bank swizzle there).
__device__ __forceinline__ void load_lds16(const char* g, char* l) {
    __builtin_amdgcn_global_load_lds(
        (const __attribute__((address_space(1))) unsigned int*)g,
        (__attribute__((address_space(3))) unsigned int*)l,
        16, 0, 0);
}

// Counted vmem wait: never drain to 0 in the main loop (T4).
#define WAITVM(n) asm volatile("s_waitcnt vmcnt(" #n ")" ::: "memory")
#define SBAR      __builtin_amdgcn_s_barrier()

// ======================= i8 MFMA PATH =======================

// x [B][D] f32 -> xi [B][D] i8 (+1/-1). float4 in, packed u32 out. Coalesced.
__global__ void pack_x_i8(const float* __restrict__ x, char* __restrict__ xi) {
    int idx = blockIdx.x * 256 + threadIdx.x;
    float4 v = ((const float4*)x)[idx];
    unsigned b0 = (v.x >= 0.f) ? 0x01u : 0xFFu;
    unsigned b1 = (v.y >= 0.f) ? 0x01u : 0xFFu;
    unsigned b2 = (v.z >= 0.f) ? 0x01u : 0xFFu;
    unsigned b3 = (v.w >= 0.f) ? 0x01u : 0xFFu;
    ((unsigned*)xi)[idx] = b0 | (b1 << 8) | (b2 << 16) | (b3 << 24);
}

// k [D][U] f32 -> kt [U][D] i8 (+1/-1), transposed via LDS 64x64 tile.
__global__ void pack_kt_i8(const float* __restrict__ k, char* __restrict__ kt) {
    __shared__ float tile[64][65];
    const int j0 = (blockIdx.x & 31) * 64;   // U tile
    const int d0 = (blockIdx.x >> 5) * 64;   // D tile
    const int tid = threadIdx.x;
    const int lane = tid & 63;
    const int wv = tid >> 6;
    for (int i = 0; i < 16; i++) {
        int row = i * 4 + wv;
        tile[row][lane] = k[(size_t)(d0 + row) * U_DIM + j0 + lane];
    }
    __syncthreads();
    const int u = tid >> 2;          // 0..63 output row (unit)
    const int g = tid & 3;           // 16-byte group along D
    union { char c[16]; int4 v; } pk;
#pragma unroll
    for (int j = 0; j < 16; j++)
        pk.c[j] = (tile[g * 16 + j][u] >= 0.f) ? (char)1 : (char)-1;
    *(int4*)(kt + (size_t)(j0 + u) * D_DIM + d0 + g * 16) = pk.v;
}

// out[i][j] = sum_k xi[i][k]*kt[j][k] + bias[j], exact in i32.
//
// R8: cross-block TLP (R7 geometry) with a CERTIFIED schedule. R7's absmax
// failure: its mid-iteration WAITVM(6) had no barrier after it, but vmcnt is
// per-wave - it cannot license reads of OTHER waves' global_load_lds data.
// Rule: counted vmcnt licenses cross-wave LDS reads only through a barrier.
//
// Geometry: 512 blocks of 256x128 (2 blocks/CU), 256 thr = 4 waves (2x2,
// wave tile 128x64, Mr=4 Nr=2, acc=128 VGPR -> ~220 total -> 2 blocks/CU,
// SEPARATE barrier domains). Ring-3 LDS: 3 x 24KB = 72KB/block; 2x72<=160.
// Per K-tile (BK=64B):
//   WAITVM(6)   (own outstanding <= stage(t+1) -> tile t landed, own)
//   SBAR        (every wave passed its WAITVM -> tile t landed CHIP-WIDE;
//                also: all waves' tile t-1 ds_reads were lgkm-drained before
//                their iter t-1 MFMAs -> buf[(t-1)%3] is free)
//   stage(t+2 -> buf[(t-1)%3])       (6 DMA loads/thread, streams under MFMA)
//   12x ds_read (tile t, kk0+kk1) ; 16x MFMA   (compiler's counted lgkm
//                                               interleaves these fine)
// Intra-block DS/MFMA serialization is hidden by the OTHER resident block
// (independent barrier domain) on the same CU - the m97/m114 implicit
// wave-level overlap. vmcnt never drains to 0 until the tail.
//
// Bank swizzle folded into the GLOBAL source (LDS dest stays linear for
// global_load_lds): within each 128B row-pair, 16B slot s <- s ^ (pair&7).
// XCD swizzle: 64 consecutive blocks per XCD (A 2MB + B 4MB working set).
__launch_bounds__(256, 2)
__global__ void gemm_i8(const char* __restrict__ xi,   // [8192][2048]
                        const char* __restrict__ kt,   // [2048][2048]
                        const float* __restrict__ bias,
                        float* __restrict__ out) {
    __shared__ uint4 lds[3][1536];   // [buf][ A:slots 0..1023 | B:1024..1535 ]

    const int tid  = threadIdx.x;
    const int lane = tid & 63;
    const int w    = tid >> 6;       // 4 waves
    const int m    = lane & 31;
    const int half = lane >> 5;

    // XCD-aware swizzle (nwg=512, 8 XCDs, 64 blocks/chunk; bijective)
    const int bid = blockIdx.x;
    const int swz = ((bid & 7) << 6) | (bid >> 3);
    const int bx  = swz & 15;        // U tile index [0,16)
    const int by  = swz >> 4;        // B tile index [0,32)
    const int rows0 = by << 8;       // 256-row block
    const int cols0 = bx << 7;       // 128-col block

    const int wr = (w >> 1) << 7;    // wave row offset: 0 or 128
    const int wc = (w & 1) << 6;     // wave col offset: 0 or 64

    v16i acc[4][2];
#pragma unroll
    for (int mi = 0; mi < 4; ++mi)
#pragma unroll
        for (int nj = 0; nj < 2; ++nj)
#pragma unroll
            for (int i = 0; i < 16; ++i) acc[mi][nj][i] = 0;

    const char* abase = xi + (size_t)rows0 * D_DIM;
    const char* bbase = kt + (size_t)cols0 * D_DIM;

    // --- staging precompute: 4 A-slots + 2 B-slots per thread ---
    // Slot s (16B units): row = s>>2, group g = s&3; pair p = s>>3,
    // sub-slot sp = s&7. Storage slot sp holds global slot sl = sp^(p&7)
    // (swizzle folded into the global source address).
    int   sbaseA[4], sbaseB[2];
    size_t goffA[4], goffB[2];
#pragma unroll
    for (int j = 0; j < 4; ++j) {
        sbaseA[j] = (w << 6) + (j << 8);         // wave-uniform LDS slot base
        const int s  = sbaseA[j] + lane;
        const int p  = s >> 3;
        const int sp = s & 7;
        const int sl = sp ^ (p & 7);
        const int gr = (p << 1) | (sl >> 2);
        const int gg = sl & 3;
        goffA[j] = (size_t)gr * D_DIM + (size_t)(gg << 4);
    }
#pragma unroll
    for (int j = 0; j < 2; ++j) {
        sbaseB[j] = (w << 6) + (j << 8);         // 512 B-slots
        const int s  = sbaseB[j] + lane;
        const int p  = s >> 3;
        const int sp = s & 7;
        const int sl = sp ^ (p & 7);
        const int gr = (p << 1) | (sl >> 2);
        const int gg = sl & 3;
        goffB[j] = (size_t)gr * D_DIM + (size_t)(gg << 4);
    }

    auto stage = [&](int t, int buf) {
        const size_t kof = (size_t)t << 6;       // t * 64 bytes along K
#pragma unroll
        for (int j = 0; j < 4; ++j)
            load_lds16(abase + goffA[j] + kof, (char*)&lds[buf][sbaseA[j]]);
#pragma unroll
        for (int j = 0; j < 2; ++j)
            load_lds16(bbase + goffB[j] + kof, (char*)&lds[buf][1024 + sbaseB[j]]);
    };

    // --- fragment read offsets (loop-invariant; swizzled) ---
    // logical: row rl, 16B group gl = kk*2+half -> byte (rl>>1)*128 + st*16
    int aoff[4][2], boff[2][2];
#pragma unroll
    for (int mi = 0; mi < 4; ++mi)
#pragma unroll
        for (int kk = 0; kk < 2; ++kk) {
            const int rl = wr + mi * 32 + m;
            const int gl = kk * 2 + half;
            const int p  = rl >> 1;
            const int st = ((((rl & 1) << 2) | gl) ^ (p & 7));
            aoff[mi][kk] = (p << 7) + (st << 4);
        }
#pragma unroll
    for (int nj = 0; nj < 2; ++nj)
#pragma unroll
        for (int kk = 0; kk < 2; ++kk) {
            const int rl = wc + nj * 32 + m;
            const int gl = kk * 2 + half;
            const int p  = rl >> 1;
            const int st = ((((rl & 1) << 2) | gl) ^ (p & 7));
            boff[nj][kk] = 16384 + (p << 7) + (st << 4);
        }

    // named fragment sets (rule #20): fE = kk0, fO = kk1 of the CURRENT tile
    struct FragK { v4i a[4]; v4i b[2]; };
    FragK fE, fO;

    auto readK = [&](FragK& f, int buf, int kk) {
        const char* Ls = (const char*)lds[buf];
#pragma unroll
        for (int mi = 0; mi < 4; ++mi)
            f.a[mi] = *(const v4i*)(Ls + aoff[mi][kk]);
#pragma unroll
        for (int nj = 0; nj < 2; ++nj)
            f.b[nj] = *(const v4i*)(Ls + boff[nj][kk]);
    };
    auto mma8 = [&](const FragK& f) {
#pragma unroll
        for (int mi = 0; mi < 4; ++mi)
#pragma unroll
            for (int nj = 0; nj < 2; ++nj)
                acc[mi][nj] = __builtin_amdgcn_mfma_i32_32x32x32_i8(
                    f.a[mi], f.b[nj], acc[mi][nj], 0, 0, 0);
    };

    // prologue: stage tiles 0,1 (12 loads/thread in flight)
    stage(0, 0); stage(1, 1);

    // main loop: tiles 0..29; stage t+2 into buf[(t+2)%3] (= buf[(t-1)%3])
    int cb = 0;                       // t % 3
#pragma unroll 1
    for (int t = 0; t < 30; ++t) {
        WAITVM(6);                    // tile t landed (own); only stage(t+1) out
        SBAR;                         // chip-wide landing; buf[(t-1)%3] free
        const int nb = (cb == 0) ? 2 : cb - 1;   // (t+2)%3
        stage(t + 2, nb);
        readK(fE, cb, 0);
        readK(fO, cb, 1);
        mma8(fE);
        mma8(fO);
        cb = (cb == 2) ? 0 : cb + 1;
    }
    // t=30 (buf 0): only stage(31)'s 6 loads outstanding
    WAITVM(6); SBAR;
    readK(fE, 0, 0); readK(fO, 0, 1); mma8(fE); mma8(fO);
    // t=31 (buf 1): drain
    WAITVM(0); SBAR;
    readK(fE, 1, 0); readK(fO, 1, 1); mma8(fE); mma8(fO);

    // C/D 32x32 layout (HW-verified): col = lane&31, row = (reg&3)+8*(reg>>2)+4*half
#pragma unroll
    for (int mi = 0; mi < 4; ++mi)
#pragma unroll
        for (int nj = 0; nj < 2; ++nj) {
            const int n = cols0 + wc + nj * 32 + m;
            const float bb = bias[n];
#pragma unroll
            for (int reg = 0; reg < 16; ++reg) {
                const int row = (reg & 3) + 8 * (reg >> 2) + 4 * half;
                const size_t grow = (size_t)(rows0 + wr + mi * 32 + row);
                out[grow * U_DIM + n] = (float)acc[mi][nj][reg] + bb;
            }
        }
}

// ======================= BIT-PATH FALLBACK (R5, proven) =======================

__global__ void pack_x_kernel(const float* __restrict__ x,
                              unsigned long long* __restrict__ xb) {
    const int gwave = (blockIdx.x * blockDim.x + threadIdx.x) >> 6;
    const int lane  = threadIdx.x & 63;
    const size_t base = (size_t)gwave * 256;
    float v0 = x[base + lane];
    float v1 = x[base + 64 + lane];
    float v2 = x[base + 128 + lane];
    float v3 = x[base + 192 + lane];
    unsigned long long m0 = __ballot(v0 >= 0.0f);
    unsigned long long m1 = __ballot(v1 >= 0.0f);
    unsigned long long m2 = __ballot(v2 >= 0.0f);
    unsigned long long m3 = __ballot(v3 >= 0.0f);
    if (lane == 0) {
        ulonglong2* p = (ulonglong2*)(xb + (base >> 6));
        ulonglong2 a; a.x = m0; a.y = m1;
        ulonglong2 b; b.x = m2; b.y = m3;
        p[0] = a;
        p[1] = b;
    }
}

__global__ void pack_k_kernel(const float* __restrict__ k,
                              unsigned long long* __restrict__ kb) {
    __shared__ float tile[64][65];
    const int j0 = (blockIdx.x & 31) * 64;
    const int d0 = (blockIdx.x >> 5) * 64;
    const int tid  = threadIdx.x;
    const int lane = tid & 63;
    const int wv   = tid >> 6;
    for (int i = 0; i < 16; i++) {
        int row = i * 4 + wv;
        tile[row][lane] = k[(size_t)(d0 + row) * U_DIM + j0 + lane];
    }
    __syncthreads();
    for (int c = wv * 16; c < wv * 16 + 16; c++) {
        float v = tile[lane][c];
        unsigned long long m = __ballot(v >= 0.0f);
        if (lane == 0) kb[(size_t)(j0 + c) * (D_DIM / 64) + (d0 >> 6)] = m;
    }
}

__launch_bounds__(512)
__global__ void bgemm_kernel(const unsigned int* __restrict__ xb,
                             const unsigned int* __restrict__ kb,
                             const float* __restrict__ bias,
                             float* __restrict__ out) {
    __shared__ unsigned int xs[128 * KWORDS];
    __shared__ unsigned int ks[128 * KWORDS];
    const int bx  = blockIdx.x;
    const int by  = blockIdx.y;
    const int tid = threadIdx.x;
    const uint4* xsrc = (const uint4*)(xb + (size_t)(by * 128) * KWORDS);
    const uint4* ksrc = (const uint4*)(kb + (size_t)(bx * 128) * KWORDS);
#pragma unroll
    for (int i = 0; i < 4; i++) {
        int flat = tid + i * 512;
        int r    = flat >> 4;
        int g    = flat & 15;
        int sg   = g ^ ((r >> 3) & 7);
        uint4 xv = xsrc[flat];
        uint4 kv = ksrc[flat];
        *((uint4*)&xs[r * KWORDS + sg * 4]) = xv;
        *((uint4*)&ks[r * KWORDS + sg * 4]) = kv;
    }
    __syncthreads();
    const int tr   = (tid >> 4) * 4;
    const int tc   = (tid & 15) * 8;
    const int xswz = ((tid >> 4) >> 1) & 7;
    const int ksw  = tid & 7;
    int acc[4][8] = {};
    for (int w4 = 0; w4 < 16; w4++) {
        const int xcol = (w4 ^ xswz) * 4;
        const int kcol = (w4 ^ ksw) * 4;
        uint4 xv[4], kv[8];
#pragma unroll
        for (int r = 0; r < 4; r++) xv[r] = *((const uint4*)&xs[(tr + r) * KWORDS + xcol]);
#pragma unroll
        for (int c = 0; c < 8; c++) kv[c] = *((const uint4*)&ks[(tc + c) * KWORDS + kcol]);
#pragma unroll
        for (int r = 0; r < 4; r++)
#pragma unroll
            for (int c = 0; c < 8; c++) {
                acc[r][c] += __popc(xv[r].x ^ kv[c].x);
                acc[r][c] += __popc(xv[r].y ^ kv[c].y);
                acc[r][c] += __popc(xv[r].z ^ kv[c].z);
                acc[r][c] += __popc(xv[r].w ^ kv[c].w);
            }
    }
    const int row0 = by * 128 + tr;
    const int col0 = bx * 128 + tc;
    const float4 b0 = *((const float4*)&bias[col0]);
    const float4 b1 = *((const float4*)&bias[col0 + 4]);
#pragma unroll
    for (int r = 0; r < 4; r++) {
        float4 o0, o1;
        o0.x = (float)(D_DIM - 2 * acc[r][0]) + b0.x;
        o0.y = (float)(D_DIM - 2 * acc[r][1]) + b0.y;
        o0.z = (float)(D_DIM - 2 * acc[r][2]) + b0.z;
        o0.w = (float)(D_DIM - 2 * acc[r][3]) + b0.w;
        o1.x = (float)(D_DIM - 2 * acc[r][4]) + b1.x;
        o1.y = (float)(D_DIM - 2 * acc[r][5]) + b1.y;
        o1.z = (float)(D_DIM - 2 * acc[r][6]) + b1.z;
        o1.w = (float)(D_DIM - 2 * acc[r][7]) + b1.w;
        float* orow = &out[(size_t)(row0 + r) * U_DIM + col0];
        *((float4*)orow)       = o0;
        *((float4*)(orow + 4)) = o1;
    }
}

// ======================= launcher =======================

extern "C" void kernel_launch(void* const* d_in, const int* in_sizes, int n_in,
                              void* d_out, int out_size, void* d_ws, size_t ws_size,
                              hipStream_t stream) {
    const float* x    = (const float*)d_in[0];   // [8192][2048]
    const float* k    = (const float*)d_in[1];   // [2048][2048]
    const float* bias = (const float*)d_in[2];   // [2048]
    float* out = (float*)d_out;

    const size_t need_i8 = (size_t)B_DIM * D_DIM + (size_t)U_DIM * D_DIM; // ~21 MB
    if (ws_size >= need_i8) {
        char* xi = (char*)d_ws;                          // 16 MB
        char* kt = xi + (size_t)B_DIM * D_DIM;           // 4 MB
        pack_x_i8<<<(B_DIM * D_DIM) / 1024, 256, 0, stream>>>(x, xi);
        pack_kt_i8<<<32 * 32, 256, 0, stream>>>(k, kt);
        gemm_i8<<<512, 256, 0, stream>>>(xi, kt, bias, out);
    } else {
        unsigned long long* xbits = (unsigned long long*)d_ws;
        unsigned long long* kbits = (unsigned long long*)((char*)d_ws + (size_t)B_DIM * (D_DIM / 8));
        pack_x_kernel<<<(B_DIM * D_DIM) / 1024, 256, 0, stream>>>(x, xbits);
        pack_k_kernel<<<32 * 32, 256, 0, stream>>>(k, kbits);
        dim3 grid(U_DIM / 128, B_DIM / 128);
        bgemm_kernel<<<grid, 512, 0, stream>>>((const unsigned int*)xbits,
                                               (const unsigned int*)kbits, bias, out);
    }
}